// Round 18
// baseline (39.482 us; speedup 1.0000x reference)
//
#include <hip/hip_runtime.h>
#include <hip/hip_bf16.h>
#include <math.h>

#define D 256
#define NPROTO 1024
#define NROWS 16384
#define WRr 13
#define WCc 18
#define WJ (WRr * WCc)
#define JSUB 59                    // ceil(WJ/4)
#define GMAT_BLOCKS (NPROTO / 4)   // 256

typedef __attribute__((ext_vector_type(8))) short short8;
typedef __attribute__((ext_vector_type(4))) float f32x4;

__device__ __forceinline__ short f2bf(float f) {
    union { __hip_bfloat16 b; short s; } u;
    u.b = __float2bfloat16(f);
    return u.s;
}

// ---- hex-grid neighborhood H[i,j], fp32 (proven R13, absmax 4.0) ----
__device__ __forceinline__ float hval(int i, int j) {
    int ri = i >> 5, ci = i & 31;
    int rj = j >> 5, cj = j & 31;
    float xi = (float)ci + 0.5f * (float)(ri & 1);
    float yi = (float)ri * 0.86602540f;
    float xj = (float)cj + 0.5f * (float)(rj & 1);
    float yj = (float)rj * 0.86602540f;
    float dx0 = xi - xj, dy0 = yi - yj;
    const float W = 32.0f;
    const float Hh = 27.7128129f;  // 32*sqrt(3)/2
    float best = 3.4e38f;
#pragma unroll
    for (int sx = -1; sx <= 1; ++sx) {
        float dx = dx0 + (float)sx * W;
#pragma unroll
        for (int sy = -1; sy <= 1; ++sy) {
            float dy = dy0 + (float)sy * Hh;
            float d2 = dx * dx + dy * dy;
            best = fminf(best, d2);
        }
    }
    return __expf(-0.5f * best);
}

// GbF layout (MFMA B-fragment order; PROVEN R6/R7): tile (Ig = i>>4, kg = k>>5)
// = 512 shorts at (Ig*8+kg)*512; lane l reads l*8 -> i = Ig*16 + (l&15),
// k = kg*32 + (l>>4)*8 .. +7 — exactly one 16x16x32 B fragment per tile.

// ---- prep: gmat only (256 blocks, 4 protos each) + out init ----
__global__ void __launch_bounds__(256) prep_kernel(
    const float* __restrict__ P, short* __restrict__ GbF,
    float* __restrict__ hsum, float* __restrict__ hp2,
    unsigned* __restrict__ out) {
    __shared__ float ht[4][WJ];
    __shared__ int jrow[WJ];
    __shared__ __align__(16) float gpart[4][4][256];
    __shared__ float hqred[4][4];
    __shared__ float hsred[4][4];
    int t = threadIdx.x;
    int bx = blockIdx.x;

    if (t < 64) out[bx * 64 + t] = 0x7f800000u;  // +inf (256*64 = 16384)

    int i0 = bx * 4;
    int r0 = i0 >> 5, c0 = i0 & 31;

    for (int u = t; u < WJ; u += 256) {
        int jr = (r0 + (u / WCc) - 6 + 32) & 31;
        int jc = (c0 + (u % WCc) - 7 + 32) & 31;
        int j = jr * 32 + jc;
        jrow[u] = j;
#pragma unroll
        for (int s = 0; s < 4; ++s) ht[s][u] = hval(i0 + s, j);
    }
    __syncthreads();

    int w = t >> 6, lane = t & 63;
    int j0 = w * JSUB;
    int j1 = (j0 + JSUB < WJ) ? j0 + JSUB : WJ;
    f32x4 g[4] = {{0.f, 0.f, 0.f, 0.f}, {0.f, 0.f, 0.f, 0.f},
                  {0.f, 0.f, 0.f, 0.f}, {0.f, 0.f, 0.f, 0.f}};
    float hqp[4] = {0.f, 0.f, 0.f, 0.f};
    float hsp[4] = {0.f, 0.f, 0.f, 0.f};
    for (int u = j0; u < j1; ++u) {
        f32x4 pv = *reinterpret_cast<const f32x4*>(P + (size_t)jrow[u] * D + lane * 4);
        float q = pv[0] * pv[0] + pv[1] * pv[1] + pv[2] * pv[2] + pv[3] * pv[3];
#pragma unroll
        for (int s = 0; s < 4; ++s) {
            float h = ht[s][u];
            g[s][0] = fmaf(h, pv[0], g[s][0]);
            g[s][1] = fmaf(h, pv[1], g[s][1]);
            g[s][2] = fmaf(h, pv[2], g[s][2]);
            g[s][3] = fmaf(h, pv[3], g[s][3]);
            hqp[s] = fmaf(h, q, hqp[s]);
            hsp[s] += h;  // lane-uniform
        }
    }
#pragma unroll
    for (int s = 0; s < 4; ++s)
        *reinterpret_cast<f32x4*>(&gpart[w][s][lane * 4]) = g[s];
#pragma unroll
    for (int s = 0; s < 4; ++s) {
#pragma unroll
        for (int off = 1; off < 64; off <<= 1) hqp[s] += __shfl_xor(hqp[s], off);
    }
    if (lane == 0) {
#pragma unroll
        for (int s = 0; s < 4; ++s) { hqred[w][s] = hqp[s]; hsred[w][s] = hsp[s]; }
    }
    __syncthreads();

    // final: sum partials; pair lanes -> 8-d chunks; write B-FRAGMENT order
    {
        int s = t >> 6;
        f32x4 gs = *reinterpret_cast<const f32x4*>(&gpart[0][s][lane * 4]);
#pragma unroll
        for (int ww = 1; ww < 4; ++ww) {
            f32x4 gp = *reinterpret_cast<const f32x4*>(&gpart[ww][s][lane * 4]);
            gs[0] += gp[0]; gs[1] += gp[1]; gs[2] += gp[2]; gs[3] += gp[3];
        }
        float h0 = __shfl_down(gs[0], 1);
        float h1 = __shfl_down(gs[1], 1);
        float h2 = __shfl_down(gs[2], 1);
        float h3 = __shfl_down(gs[3], 1);
        if (!(lane & 1)) {
            int c = lane >> 1;          // d-chunk: d = c*8 .. c*8+7
            int kg = c >> 2;            // 32-k group
            int q = c & 3;              // 8-d sub-chunk
            int i = i0 + s;
            int Ig = i >> 4;
            short8 wv;
            wv[0] = f2bf(gs[0]); wv[1] = f2bf(gs[1]); wv[2] = f2bf(gs[2]); wv[3] = f2bf(gs[3]);
            wv[4] = f2bf(h0);    wv[5] = f2bf(h1);    wv[6] = f2bf(h2);    wv[7] = f2bf(h3);
            *reinterpret_cast<short8*>(
                GbF + (((size_t)Ig * 8 + kg) << 9) + ((i & 15) + 16 * q) * 8) = wv;
        }
    }
    if (t < 4) {
        hsum[i0 + t] = hsred[0][t] + hsred[1][t] + hsred[2][t] + hsred[3][t];
    } else if (t < 8) {
        int s = t - 4;
        hp2[i0 + s] = hqred[0][s] + hqred[1][s] + hqred[2][s] + hqred[3][s];
    }
}

// ---- som18: persistent-X LDS (64KB, 8 kt-planes, slot-swizzled), converted
//      ONCE per block from f32 X; K-loop is BARRIER-FREE: A from read-only
//      LDS (4 ds_read/wave/phase), B fragment-ordered straight to VGPRs from
//      L2-resident GbF (pipelined 1 phase ahead, compiler-managed vmcnt).
//      2 blocks/CU. x2 via ws (self-produced/self-consumed per block). ----
__global__ void __launch_bounds__(256, 2) som18_kernel(
    const float* __restrict__ X, const short* __restrict__ GbF,
    const float* __restrict__ hsum, const float* __restrict__ hp2,
    float* __restrict__ x2g, unsigned* __restrict__ out) {
    __shared__ __align__(16) short Xl[8][128 * 32];  // 64KB exactly

    const int t = threadIdx.x;
    const int lane = t & 63;
    const int wid = t >> 6;
    const int wr = wid >> 1;   // n half (64 rows)
    const int wc = wid & 1;    // i half (64 cols)
    const int lm = lane & 15;
    const int lq = lane >> 4;
    const int key = (lm & 3) ^ ((lm >> 2) & 3);

    // XCD-bijective swizzle: the 8 i-blocks of one n0 share an XCD -> X rows
    // HBM-read once, 7x L2 hits; GbF slice L2-resident.
    const int bx = blockIdx.x;
    const int w1024 = ((bx & 7) << 7) | (bx >> 3);
    const int n0 = (w1024 >> 3) * 128;
    const int ib0 = (w1024 & 7) * 128;

    // ---- one-time conversion: 128 rows f32 -> bf16 into Xl, x2 to ws ----
    {
        int g = t & 31;          // k-chunk of 8 f32
        int ktc = g >> 2;
        int slot = g & 3;
        int rsub = t >> 5;       // 0..7
#pragma unroll
        for (int it = 0; it < 16; ++it) {
            int row = it * 8 + rsub;
            const float4* src = reinterpret_cast<const float4*>(
                X + (size_t)(n0 + row) * D) + g * 2;
            float4 a = src[0], b = src[1];
            float s = a.x * a.x + a.y * a.y + a.z * a.z + a.w * a.w +
                      b.x * b.x + b.y * b.y + b.z * b.z + b.w * b.w;
            s += __shfl_xor(s, 1);
            s += __shfl_xor(s, 2);
            s += __shfl_xor(s, 4);
            s += __shfl_xor(s, 8);
            s += __shfl_xor(s, 16);
            if (g == 0) x2g[n0 + row] = s;
            short8 w;
            w[0] = f2bf(a.x); w[1] = f2bf(a.y); w[2] = f2bf(a.z); w[3] = f2bf(a.w);
            w[4] = f2bf(b.x); w[5] = f2bf(b.y); w[6] = f2bf(b.z); w[7] = f2bf(b.w);
            int kr = (row & 3) ^ ((row >> 2) & 3);
            *reinterpret_cast<short8*>(
                &Xl[ktc][row * 32 + ((slot ^ kr) << 3)]) = w;
        }
    }
    __syncthreads();

    // ---- barrier-free K-loop: 8 phases fully unrolled ----
    const int Igb = (ib0 >> 4) + wc * 4;
    f32x4 acc[4][4];
#pragma unroll
    for (int m = 0; m < 4; ++m)
#pragma unroll
        for (int n = 0; n < 4; ++n) acc[m][n] = (f32x4){0.f, 0.f, 0.f, 0.f};

    short8 bn[4];
#pragma unroll
    for (int n = 0; n < 4; ++n)
        bn[n] = *reinterpret_cast<const short8*>(
            GbF + (((size_t)(Igb + n) * 8 + 0) << 9) + lane * 8);

#pragma unroll
    for (int kt = 0; kt < 8; ++kt) {
        short8 bc[4];
#pragma unroll
        for (int n = 0; n < 4; ++n) bc[n] = bn[n];
        short8 a[4];
#pragma unroll
        for (int m = 0; m < 4; ++m)
            a[m] = *reinterpret_cast<const short8*>(
                &Xl[kt][(wr * 64 + m * 16 + lm) * 32 + ((lq ^ key) << 3)]);
        if (kt < 7) {
#pragma unroll
            for (int n = 0; n < 4; ++n)
                bn[n] = *reinterpret_cast<const short8*>(
                    GbF + (((size_t)(Igb + n) * 8 + kt + 1) << 9) + lane * 8);
        }
        __builtin_amdgcn_s_setprio(1);
#pragma unroll
        for (int m = 0; m < 4; ++m)
#pragma unroll
            for (int n = 0; n < 4; ++n)
                acc[m][n] = __builtin_amdgcn_mfma_f32_16x16x32_bf16(a[m], bc[n], acc[m][n], 0, 0, 0);
        __builtin_amdgcn_s_setprio(0);
    }

    // ---- epilogue: e = hsum*x2 + hp2 - 2*acc; min over block's 128 i ----
    float x2v[4][4];
#pragma unroll
    for (int m = 0; m < 4; ++m) {
        f32x4 xv = *reinterpret_cast<const f32x4*>(
            &x2g[n0 + wr * 64 + m * 16 + lq * 4]);
#pragma unroll
        for (int j = 0; j < 4; ++j) x2v[m][j] = xv[j];
    }

    float rmin[4][4];
#pragma unroll
    for (int m = 0; m < 4; ++m)
#pragma unroll
        for (int j = 0; j < 4; ++j) rmin[m][j] = 3.4e38f;

#pragma unroll
    for (int ni = 0; ni < 4; ++ni) {
        int ig = ib0 + wc * 64 + ni * 16 + lm;
        float hs = hsum[ig];
        float hq = hp2[ig];
#pragma unroll
        for (int m = 0; m < 4; ++m)
#pragma unroll
            for (int j = 0; j < 4; ++j) {
                float e = fmaf(hs, x2v[m][j], hq) - 2.0f * acc[m][ni][j];
                rmin[m][j] = fminf(rmin[m][j], e);
            }
    }

#pragma unroll
    for (int m = 0; m < 4; ++m)
#pragma unroll
        for (int j = 0; j < 4; ++j) {
            float v = rmin[m][j];
            v = fminf(v, __shfl_xor(v, 1));
            v = fminf(v, __shfl_xor(v, 2));
            v = fminf(v, __shfl_xor(v, 4));
            v = fminf(v, __shfl_xor(v, 8));
            rmin[m][j] = v;
        }

    __syncthreads();                       // Xl dead -> reuse as reduction buf
    float* red = reinterpret_cast<float*>(&Xl[0][0]);  // [2][128]
    if (lm == 0) {
#pragma unroll
        for (int m = 0; m < 4; ++m)
#pragma unroll
            for (int j = 0; j < 4; ++j)
                red[wc * 128 + wr * 64 + m * 16 + lq * 4 + j] = rmin[m][j];
    }
    __syncthreads();
    if (t < 128) {
        float v = fminf(red[t], red[128 + t]);
        atomicMin(out + n0 + t, __float_as_uint(0.5f * v));
    }
}

extern "C" void kernel_launch(void* const* d_in, const int* in_sizes, int n_in,
                              void* d_out, int out_size, void* d_ws, size_t ws_size,
                              hipStream_t stream) {
    const float* X = (const float*)d_in[0];  // [16384, 256]
    const float* P = (const float*)d_in[1];  // [1024, 256]
    unsigned* out = (unsigned*)d_out;        // [1, 16384] f32 as uint
    (void)in_sizes; (void)n_in; (void)out_size; (void)ws_size;

    float* ws = (float*)d_ws;
    float* hsum = ws + 1024;             // 1024 f32
    float* hp2 = ws + 2048;              // 1024 f32
    float* x2g = ws + 4096;              // 16384 f32
    short* GbF = (short*)(ws + 32768);   // 1024*256 bf16 frag-ordered (512KB)

    prep_kernel<<<GMAT_BLOCKS, 256, 0, stream>>>(P, GbF, hsum, hp2, out);
    som18_kernel<<<1024, 256, 0, stream>>>(X, GbF, hsum, hp2, x2g, out);
}

// Round 19
// 31.474 us; speedup vs baseline: 1.2544x; 1.2544x over previous
//
#include <hip/hip_runtime.h>
#include <hip/hip_bf16.h>
#include <math.h>

#define D 256
#define NPROTO 1024
#define NROWS 16384
#define WRr 13
#define WCc 18
#define WJ (WRr * WCc)
#define JSUB 59                    // ceil(WJ/4)
#define GMAT_BLOCKS (NPROTO / 4)   // 256
#define XPREP_BLOCKS (NROWS / 32)  // 512

#define WAITVM(N) asm volatile("s_waitcnt vmcnt(" #N ")" ::: "memory")

typedef __attribute__((ext_vector_type(8))) short short8;
typedef __attribute__((ext_vector_type(4))) float f32x4;

// slot-swizzle key for 64-byte rows (4 slots of 16B); same key on ws write
// and LDS read (rule 21). 2-way max bank aliasing (free, m136).
__device__ __forceinline__ int swz_key(int row) {
    return (row & 3) ^ ((row >> 2) & 3);
}

__device__ __forceinline__ short f2bf(float f) {
    union { __hip_bfloat16 b; short s; } u;
    u.b = __float2bfloat16(f);
    return u.s;
}

__device__ __forceinline__ void gload_lds16(void* lds, const void* g) {
    __builtin_amdgcn_global_load_lds(
        (const __attribute__((address_space(1))) unsigned*)g,
        (__attribute__((address_space(3))) unsigned*)lds, 16, 0, 0);
}

// ---- hex-grid neighborhood H[i,j], fp32 (abs err ~1e-6 on h; energies need
//      only ~1e-1 — fp64 exp removed from gmat's critical path) ----
__device__ __forceinline__ float hval(int i, int j) {
    int ri = i >> 5, ci = i & 31;
    int rj = j >> 5, cj = j & 31;
    float xi = (float)ci + 0.5f * (float)(ri & 1);
    float yi = (float)ri * 0.86602540f;
    float xj = (float)cj + 0.5f * (float)(rj & 1);
    float yj = (float)rj * 0.86602540f;
    float dx0 = xi - xj, dy0 = yi - yj;
    const float W = 32.0f;
    const float Hh = 27.7128129f;  // 32*sqrt(3)/2
    float best = 3.4e38f;
#pragma unroll
    for (int sx = -1; sx <= 1; ++sx) {
        float dx = dx0 + (float)sx * W;
#pragma unroll
        for (int sy = -1; sy <= 1; ++sy) {
            float dy = dy0 + (float)sy * Hh;
            float d2 = dx * dx + dy * dy;
            best = fminf(best, d2);
        }
    }
    return __expf(-0.5f * best);
}

// ws layouts (kt-major, slot-swizzled), k = kt*32 + slot*8 + e:
//  XgS short idx = kt*(NROWS*32) + row*32 + ((slot ^ key(row))*8) + e
//  GbS short idx = kt*(NPROTO*32) + i*32  + ((slot ^ key(i))*8) + e

// ---- prep: role-split.
//  bx < 256:   gmat -> GbS + hsum + hp2  (sparse 13x18 torus window, j-split)
//  bx >= 256:  xprep -> XgS + x2 + out=+inf, XCD-ALIGNED: block xb (XCD=xb%8)
//              writes rows [2048*(xb%8) + 32*(xb/8), +32) — the exact slice
//              som's XCD-(xb%8) blocks consume -> producer/consumer same L2.
__global__ void __launch_bounds__(256) prep_kernel(
    const float* __restrict__ X, const float* __restrict__ P,
    short* __restrict__ XgS, short* __restrict__ GbS,
    float* __restrict__ x2, float* __restrict__ hsum, float* __restrict__ hp2,
    unsigned* __restrict__ out) {
    int t = threadIdx.x;
    int bx = blockIdx.x;

    if (bx >= GMAT_BLOCKS) {
        // ---------------- xprep: 32 rows, XCD-aligned base ----------------
        int xb = bx - GMAT_BLOCKS;
        int base0 = (xb & 7) * 2048 + (xb >> 3) * 32;
        int g = t & 31;          // k-chunk: k = g*8..+7
        int kt = g >> 2;
        int slot = g & 3;
#pragma unroll
        for (int it = 0; it < 4; ++it) {
            int row = base0 + it * 8 + (t >> 5);
            const float4* src = reinterpret_cast<const float4*>(X + (size_t)row * D) + g * 2;
            float4 a = src[0], b = src[1];
            float s = a.x * a.x + a.y * a.y + a.z * a.z + a.w * a.w +
                      b.x * b.x + b.y * b.y + b.z * b.z + b.w * b.w;
            s += __shfl_xor(s, 1);
            s += __shfl_xor(s, 2);
            s += __shfl_xor(s, 4);
            s += __shfl_xor(s, 8);
            s += __shfl_xor(s, 16);
            if (g == 0) x2[row] = s;
            short8 w;
            w[0] = f2bf(a.x); w[1] = f2bf(a.y); w[2] = f2bf(a.z); w[3] = f2bf(a.w);
            w[4] = f2bf(b.x); w[5] = f2bf(b.y); w[6] = f2bf(b.z); w[7] = f2bf(b.w);
            *reinterpret_cast<short8*>(
                XgS + (size_t)kt * (NROWS * 32) + (size_t)row * 32 +
                ((slot ^ swz_key(row)) << 3)) = w;
        }
        if (t < 32) out[base0 + t] = 0x7f800000u;  // +inf
        return;
    }

    // ---------------- gmat ----------------
    __shared__ float ht[4][WJ];
    __shared__ int jrow[WJ];
    __shared__ __align__(16) float gpart[4][4][256];
    __shared__ float hqred[4][4];
    __shared__ float hsred[4][4];
    int i0 = bx * 4;
    int r0 = i0 >> 5, c0 = i0 & 31;

    for (int u = t; u < WJ; u += 256) {
        int jr = (r0 + (u / WCc) - 6 + 32) & 31;
        int jc = (c0 + (u % WCc) - 7 + 32) & 31;
        int j = jr * 32 + jc;
        jrow[u] = j;
#pragma unroll
        for (int s = 0; s < 4; ++s) ht[s][u] = hval(i0 + s, j);
    }
    __syncthreads();

    int w = t >> 6, lane = t & 63;
    int j0 = w * JSUB;
    int j1 = (j0 + JSUB < WJ) ? j0 + JSUB : WJ;
    f32x4 g[4] = {{0.f, 0.f, 0.f, 0.f}, {0.f, 0.f, 0.f, 0.f},
                  {0.f, 0.f, 0.f, 0.f}, {0.f, 0.f, 0.f, 0.f}};
    float hqp[4] = {0.f, 0.f, 0.f, 0.f};
    float hsp[4] = {0.f, 0.f, 0.f, 0.f};
    for (int u = j0; u < j1; ++u) {
        f32x4 pv = *reinterpret_cast<const f32x4*>(P + (size_t)jrow[u] * D + lane * 4);
        float q = pv[0] * pv[0] + pv[1] * pv[1] + pv[2] * pv[2] + pv[3] * pv[3];
#pragma unroll
        for (int s = 0; s < 4; ++s) {
            float h = ht[s][u];
            g[s][0] = fmaf(h, pv[0], g[s][0]);
            g[s][1] = fmaf(h, pv[1], g[s][1]);
            g[s][2] = fmaf(h, pv[2], g[s][2]);
            g[s][3] = fmaf(h, pv[3], g[s][3]);
            hqp[s] = fmaf(h, q, hqp[s]);
            hsp[s] += h;  // lane-uniform
        }
    }
#pragma unroll
    for (int s = 0; s < 4; ++s)
        *reinterpret_cast<f32x4*>(&gpart[w][s][lane * 4]) = g[s];
#pragma unroll
    for (int s = 0; s < 4; ++s) {
#pragma unroll
        for (int off = 1; off < 64; off <<= 1) hqp[s] += __shfl_xor(hqp[s], off);
    }
    if (lane == 0) {
#pragma unroll
        for (int s = 0; s < 4; ++s) { hqred[w][s] = hqp[s]; hsred[w][s] = hsp[s]; }
    }
    __syncthreads();

    {
        int s = t >> 6;
        f32x4 gs = *reinterpret_cast<const f32x4*>(&gpart[0][s][lane * 4]);
#pragma unroll
        for (int ww = 1; ww < 4; ++ww) {
            f32x4 gp = *reinterpret_cast<const f32x4*>(&gpart[ww][s][lane * 4]);
            gs[0] += gp[0]; gs[1] += gp[1]; gs[2] += gp[2]; gs[3] += gp[3];
        }
        float h0 = __shfl_down(gs[0], 1);
        float h1 = __shfl_down(gs[1], 1);
        float h2 = __shfl_down(gs[2], 1);
        float h3 = __shfl_down(gs[3], 1);
        if (!(lane & 1)) {
            int c = lane >> 1;   // 16B chunk: k = c*8..+7
            int kt = c >> 2;
            int slot = c & 3;
            int i = i0 + s;
            short8 wv;
            wv[0] = f2bf(gs[0]); wv[1] = f2bf(gs[1]); wv[2] = f2bf(gs[2]); wv[3] = f2bf(gs[3]);
            wv[4] = f2bf(h0);    wv[5] = f2bf(h1);    wv[6] = f2bf(h2);    wv[7] = f2bf(h3);
            *reinterpret_cast<short8*>(
                GbS + (size_t)kt * (NPROTO * 32) + (size_t)i * 32 +
                ((slot ^ swz_key(i)) << 3)) = wv;
        }
    }
    if (t < 4) {
        hsum[i0 + t] = hsred[0][t] + hsred[1][t] + hsred[2][t] + hsred[3][t];
    } else if (t < 8) {
        int s = t - 4;
        hp2[i0 + s] = hqred[0][s] + hqred[1][s] + hqred[2][s] + hqred[3][s];
    }
}

// ---- som8: 128n x 128i tile, BK=32, 8 phases, dbuf 32KB LDS -> 4 blocks/CU.
//      Counted vmcnt(4) (T3+T4), XCD-bijective block swizzle (T1),
//      slot-swizzled LDS (T2), setprio around MFMA (T5). ----
__global__ void __launch_bounds__(256, 4) som8_kernel(
    const short* __restrict__ XgS, const short* __restrict__ GbS,
    const float* __restrict__ x2, const float* __restrict__ hsum,
    const float* __restrict__ hp2, unsigned* __restrict__ out) {
    __shared__ __align__(16) short Xs[2][128 * 32];  // 8KB each
    __shared__ __align__(16) short Gs[2][128 * 32];
    __shared__ float red[2][128];

    const int t = threadIdx.x;
    const int lane = t & 63;
    const int wid = t >> 6;
    const int wr = wid >> 1;   // n half (64 rows)
    const int wc = wid & 1;    // i half (64 cols)
    const int lm = lane & 15;
    const int lq = lane >> 4;
    const int key = (lm & 3) ^ ((lm >> 2) & 3);

    // XCD-bijective swizzle: 1024 blocks = 8 XCDs x 128; XCD k covers
    // nb in [16k,16k+16) x all 8 ib -> 1MB XgS + 512KB GbS per XCD L2.
    const int lin = blockIdx.x;
    const int w1024 = ((lin & 7) << 7) | (lin >> 3);
    const int n0 = (w1024 >> 3) * 128;
    const int ib0 = (w1024 & 7) * 128;

    f32x4 acc[4][4];
#pragma unroll
    for (int m = 0; m < 4; ++m)
#pragma unroll
        for (int n = 0; n < 4; ++n) acc[m][n] = (f32x4){0.f, 0.f, 0.f, 0.f};

    auto stage = [&](int b, int kt) {
        // linear dest; sources pre-swizzled in ws -> contiguous reads
#pragma unroll
        for (int q = 0; q < 2; ++q)
            gload_lds16((char*)(&Xs[b][0]) + q * 4096 + t * 16,
                        XgS + (size_t)kt * (NROWS * 32) +
                        (size_t)(n0 + q * 64 + (t >> 2)) * 32 + ((t & 3) << 3));
#pragma unroll
        for (int q = 0; q < 2; ++q)
            gload_lds16((char*)(&Gs[b][0]) + q * 4096 + t * 16,
                        GbS + (size_t)kt * (NPROTO * 32) +
                        (size_t)(ib0 + q * 64 + (t >> 2)) * 32 + ((t & 3) << 3));
    };

    stage(0, 0);  // 4 VMEM outstanding

#pragma unroll
    for (int p = 0; p < 8; ++p) {
        if (p < 7) stage((p + 1) & 1, p + 1);          // +4 -> 8 outstanding
        if (p < 7) { WAITVM(4); } else { WAITVM(0); }  // retire phase-p stage
        __builtin_amdgcn_sched_barrier(0);
        __builtin_amdgcn_s_barrier();

        const short* xb = &Xs[p & 1][0];
        const short* gb = &Gs[p & 1][0];
        const int so = (lq ^ key) << 3;
        short8 a[4], b[4];
#pragma unroll
        for (int m = 0; m < 4; ++m)
            a[m] = *reinterpret_cast<const short8*>(&xb[(wr * 64 + m * 16 + lm) * 32 + so]);
#pragma unroll
        for (int n = 0; n < 4; ++n)
            b[n] = *reinterpret_cast<const short8*>(&gb[(wc * 64 + n * 16 + lm) * 32 + so]);
        __builtin_amdgcn_s_setprio(1);
#pragma unroll
        for (int m = 0; m < 4; ++m)
#pragma unroll
            for (int n = 0; n < 4; ++n)
                acc[m][n] = __builtin_amdgcn_mfma_f32_16x16x32_bf16(a[m], b[n], acc[m][n], 0, 0, 0);
        __builtin_amdgcn_s_setprio(0);
        __builtin_amdgcn_s_barrier();
    }

    // ---- epilogue: e = hsum*x2 + hp2 - 2*acc; min over block's 128 i ----
    float x2v[4][4];
#pragma unroll
    for (int m = 0; m < 4; ++m)
#pragma unroll
        for (int j = 0; j < 4; ++j)
            x2v[m][j] = x2[n0 + wr * 64 + m * 16 + lq * 4 + j];

    float rmin[4][4];
#pragma unroll
    for (int m = 0; m < 4; ++m)
#pragma unroll
        for (int j = 0; j < 4; ++j) rmin[m][j] = 3.4e38f;

#pragma unroll
    for (int ni = 0; ni < 4; ++ni) {
        int ig = ib0 + wc * 64 + ni * 16 + lm;
        float hs = hsum[ig];
        float hq = hp2[ig];
#pragma unroll
        for (int m = 0; m < 4; ++m)
#pragma unroll
            for (int j = 0; j < 4; ++j) {
                float e = fmaf(hs, x2v[m][j], hq) - 2.0f * acc[m][ni][j];
                rmin[m][j] = fminf(rmin[m][j], e);
            }
    }

#pragma unroll
    for (int m = 0; m < 4; ++m)
#pragma unroll
        for (int j = 0; j < 4; ++j) {
            float v = rmin[m][j];
            v = fminf(v, __shfl_xor(v, 1));
            v = fminf(v, __shfl_xor(v, 2));
            v = fminf(v, __shfl_xor(v, 4));
            v = fminf(v, __shfl_xor(v, 8));
            rmin[m][j] = v;
        }
    if (lm == 0) {
#pragma unroll
        for (int m = 0; m < 4; ++m)
#pragma unroll
            for (int j = 0; j < 4; ++j)
                red[wc][wr * 64 + m * 16 + lq * 4 + j] = rmin[m][j];
    }
    __syncthreads();
    if (t < 128) {
        float v = fminf(red[0][t], red[1][t]);
        atomicMin(out + n0 + t, __float_as_uint(0.5f * v));
    }
}

extern "C" void kernel_launch(void* const* d_in, const int* in_sizes, int n_in,
                              void* d_out, int out_size, void* d_ws, size_t ws_size,
                              hipStream_t stream) {
    const float* X = (const float*)d_in[0];  // [16384, 256]
    const float* P = (const float*)d_in[1];  // [1024, 256]
    unsigned* out = (unsigned*)d_out;        // [1, 16384] f32 as uint
    (void)in_sizes; (void)n_in; (void)out_size; (void)ws_size;

    float* ws = (float*)d_ws;
    float* hsum = ws + 1024;             // 1024 f32
    float* hp2 = ws + 2048;              // 1024 f32
    float* x2 = ws + 4096;               // 16384 f32
    short* GbS = (short*)(ws + 32768);   // 1024*256 bf16 kt-major swizzled (512KB)
    short* XgS = (short*)(ws + 262144);  // 16384*256 bf16 kt-major swizzled (8.4MB)

    prep_kernel<<<GMAT_BLOCKS + XPREP_BLOCKS, 256, 0, stream>>>(
        X, P, XgS, GbS, x2, hsum, hp2, out);
    som8_kernel<<<1024, 256, 0, stream>>>(XgS, GbS, x2, hsum, hp2, out);
}